// Round 7
// baseline (371.442 us; speedup 1.0000x reference)
//
#include <hip/hip_runtime.h>
#include <hip/hip_bf16.h>
#include <math.h>

#define B    512
#define INU  8
#define IC   1152
#define NU   10
#define US   16
#define JU   160            // NU*US
#define KI   9216           // INU*IC
#define BETAC 1.45f
#define NSPLIT 32           // s_gemm k-chunks; KC = KI/NSPLIT
#define KC 288              // 9 MFMA steps of 32; divides IC
#define NBS 2               // b_update batch splits (256 each)
#define NP  16              // bp p-slices = 8 ki-groups * NBS

typedef __attribute__((ext_vector_type(8))) __bf16 bf16x8;
typedef __attribute__((ext_vector_type(4))) float floatx4;

static __device__ __forceinline__ unsigned short f2bf(float f) {
  unsigned u = __builtin_bit_cast(unsigned, f);
  u = (u + 0x7fffu + ((u >> 16) & 1u)) >> 16;   // RNE
  return (unsigned short)u;
}
static __device__ __forceinline__ float bf2f(unsigned short h) {
  return __builtin_bit_cast(float, ((unsigned)h) << 16);
}
// 8 bf16 * 8 fp32 scale -> 8 bf16 (packed RNE converts)
static __device__ __forceinline__ uint4 scale8(uint4 wv, float4 cA, float4 cB) {
  union { uint4 u; unsigned short s[8]; } in;
  in.u = wv;
  union { uint4 u; __hip_bfloat162 h[4]; } o;
  o.h[0] = __float22bfloat162_rn(make_float2(bf2f(in.s[0]) * cA.x, bf2f(in.s[1]) * cA.y));
  o.h[1] = __float22bfloat162_rn(make_float2(bf2f(in.s[2]) * cA.z, bf2f(in.s[3]) * cA.w));
  o.h[2] = __float22bfloat162_rn(make_float2(bf2f(in.s[4]) * cB.x, bf2f(in.s[5]) * cB.y));
  o.h[3] = __float22bfloat162_rn(make_float2(bf2f(in.s[6]) * cB.z, bf2f(in.s[7]) * cB.w));
  return o.u;
}

// ---------------------------------------------------------------------------
// prep (one-time): blocks [0,1152): x -> xb bf16 [b][ki] + xT bf16 [ki][b]
// (64x64 LDS transpose). blocks [1152,1296): W LDS-tiled -> Wt bf16 [ju][ki]
// (MFMA B layout) + Wc = Wt * (1/IC) (iteration-0 scaled weights) + Wr fp32
// [ki][ju] (coalesced epilogue reads). Block 0 zeroes the tail counters
// (3*8 for GS + 2 for UC; workspace is re-poisoned every replay).
// ---------------------------------------------------------------------------
__global__ __launch_bounds__(256) void prep_kernel(
    const float* __restrict__ x, const float* __restrict__ W,
    unsigned short* __restrict__ xb, unsigned short* __restrict__ xT,
    unsigned short* __restrict__ Wt, unsigned short* __restrict__ Wc,
    float* __restrict__ Wr, int* __restrict__ cnts) {
  __shared__ float ts[32 * 322];    // 41.2 KB (x-part uses first 64*65)
  int id = blockIdx.x;
  int t = threadIdx.x;
  if (id == 0 && t < 26) cnts[t] = 0;
  if (id < 1152) {
    int k0 = (id % 144) * 64;
    int b0 = (id / 144) * 64;
#pragma unroll
    for (int r = 0; r < 16; ++r) {
      int idx = t + 256 * r;
      int br = idx >> 6, kc = idx & 63;
      float v = x[(size_t)(b0 + br) * KI + k0 + kc];
      ts[br * 65 + kc] = v;
      xb[(size_t)(b0 + br) * KI + k0 + kc] = f2bf(v);
    }
    __syncthreads();
#pragma unroll
    for (int r = 0; r < 8; ++r) {
      int idx = t + 256 * r;            // 0..2047
      int kr = idx >> 5, bc = (idx & 31) * 2;
      unsigned lo = f2bf(ts[bc * 65 + kr]);
      unsigned hi = f2bf(ts[(bc + 1) * 65 + kr]);
      *(unsigned*)&xT[(size_t)(k0 + kr) * B + b0 + bc] = lo | (hi << 16);
    }
  } else {
    int wid = id - 1152;              // 0..143
    int i0 = (wid >> 2) * 32;         // 36 i-chunks
    int c0 = (wid & 3) * 320;         // 4 c-chunks of W's 1280-wide rows
#pragma unroll
    for (int r = 0; r < 20; ++r) {
      int q = t + 256 * r;            // < 5120 float2
      int il = q / 160, c = (q - il * 160) * 2;
      *(float2*)&ts[il * 322 + c] =
          *(const float2*)&W[(size_t)(i0 + il) * 1280 + c0 + c];
    }
    __syncthreads();
    {
      const float cinv = 1.0f / (float)IC;
      int il2 = (t & 15) * 2;
      for (int p = (t >> 4); p < 320; p += 16) {
        int c = c0 + p;
        int ju = c >> 3, k = c & 7;
        unsigned lo = f2bf(ts[il2 * 322 + p]);
        unsigned hi = f2bf(ts[(il2 + 1) * 322 + p]);
        *(unsigned*)&Wt[(size_t)ju * KI + k * IC + i0 + il2] = lo | (hi << 16);
        unsigned lo2 = f2bf(bf2f((unsigned short)lo) * cinv);
        unsigned hi2 = f2bf(bf2f((unsigned short)hi) * cinv);
        *(unsigned*)&Wc[(size_t)ju * KI + k * IC + i0 + il2] = lo2 | (hi2 << 16);
      }
    }
    int ju0 = c0 >> 3;
    for (int q = t; q < 8 * 32 * 40; q += 256) {
      int k = q / 1280;
      int il = (q / 40) & 31;
      int jl = q - (q / 40) * 40;
      Wr[((size_t)k * IC + i0 + il) * JU + ju0 + jl] = ts[il * 322 + jl * 8 + k];
    }
  }
}

// ---------------------------------------------------------------------------
// gs_kernel = s_gemm + tail-fused squash (split-K last-block pattern):
// GEMM: sp[b][y][j0+..] = sum_{ki in chunk y} xb * Wc (round-4 body).
// Tail: per b-tile counter; after all 64 (y,z) blocks of a b-tile land,
// the z==0 blocks (one per y) squash 2 b's each: sv = sum_y sp, fac from
// the axis=1 quirk, vT bf16 [ju][b] (+ out fp32 on last iter).
// Fence/atomic protocol identical to the round-3 kernel that passed.
// Grid: (8, 32, 2) x 256 = 512 blocks, all co-resident (<=6 blocks/CU fit).
// ---------------------------------------------------------------------------
__global__ __launch_bounds__(256) void gs_kernel(
    const unsigned short* __restrict__ xb, const unsigned short* __restrict__ Wc,
    float* __restrict__ sp, unsigned short* __restrict__ vT,
    float* __restrict__ out, int* __restrict__ cnt) {
  int b0 = blockIdx.x * 64;
  int kbase = blockIdx.y * KC;
  int j0 = blockIdx.z * 80;           // j-half row offset
  int t = threadIdx.x;
  int w = t >> 6, lane = t & 63, col = lane & 15, quad = lane >> 4;
  __shared__ unsigned short xs[2][64 * 40];   // pad 40: <=2-way (free)
  __shared__ unsigned short ms[2][80 * 40];
  __shared__ float sv[2][JU];
  __shared__ float fac[2][US];

  int xrow = t >> 2, xc = (t & 3) * 8;
  int mrow0 = t >> 2, mrow1 = 64 + (t >> 2);  // rows 64..79 by t<64
  int mc = (t & 3) * 8;

  uint4 xv, m0, m1;
  auto prefetch = [&](int k0) {
    xv = *(const uint4*)&xb[(size_t)(b0 + xrow) * KI + k0 + xc];
    m0 = *(const uint4*)&Wc[(size_t)(j0 + mrow0) * KI + k0 + mc];
    if (t < 64) m1 = *(const uint4*)&Wc[(size_t)(j0 + mrow1) * KI + k0 + mc];
  };
  auto commit = [&](int pb) {
    *(uint4*)&xs[pb][xrow * 40 + xc] = xv;
    *(uint4*)&ms[pb][mrow0 * 40 + mc] = m0;
    if (t < 64) *(uint4*)&ms[pb][mrow1 * 40 + mc] = m1;
  };
  floatx4 acc[5];
#pragma unroll
  for (int jt = 0; jt < 5; ++jt) acc[jt] = (floatx4){0.f, 0.f, 0.f, 0.f};
  const int nsteps = KC >> 5;  // 9
  prefetch(kbase);
  commit(0);
  prefetch(kbase + 32);
  for (int s = 0; s < nsteps; ++s) {
    __syncthreads();                       // buf[s&1] complete for all waves
    if (s + 1 < nsteps) commit((s + 1) & 1);
    if (s + 2 < nsteps) prefetch(kbase + (s + 2) * 32);
    bf16x8 a = *(bf16x8*)&xs[s & 1][(w * 16 + col) * 40 + quad * 8];
#pragma unroll
    for (int jt = 0; jt < 5; ++jt) {
      bf16x8 bb = *(bf16x8*)&ms[s & 1][(jt * 16 + col) * 40 + quad * 8];
      acc[jt] = __builtin_amdgcn_mfma_f32_16x16x32_bf16(a, bb, acc[jt], 0, 0, 0);
    }
  }
#pragma unroll
  for (int jt = 0; jt < 5; ++jt)
#pragma unroll
    for (int r = 0; r < 4; ++r) {
      int b = b0 + w * 16 + quad * 4 + r;
      sp[((size_t)b * NSPLIT + blockIdx.y) * JU + j0 + jt * 16 + col] = acc[jt][r];
    }

  // ---- tail: signal, then z==0 blocks squash 2 b's ----
  __syncthreads();                 // all waves' sp stores drained (vmcnt@barrier)
  if (t == 0) {
    __threadfence();               // release: cross-XCD visibility
    __hip_atomic_fetch_add(cnt + blockIdx.x, 1, __ATOMIC_RELAXED,
                           __HIP_MEMORY_SCOPE_AGENT);
  }
  if (blockIdx.z != 0) return;
  if (t == 0) {
    while (__hip_atomic_load(cnt + blockIdx.x, __ATOMIC_RELAXED,
                             __HIP_MEMORY_SCOPE_AGENT) < 64)
      __builtin_amdgcn_s_sleep(1);
    __threadfence();               // acquire: invalidate before sp reads
  }
  __syncthreads();
  if (t < JU) {
#pragma unroll
    for (int bi = 0; bi < 2; ++bi) {
      int b = b0 + blockIdx.y * 2 + bi;
      float s = 0.0f;
#pragma unroll
      for (int k = 0; k < NSPLIT; ++k) s += sp[((size_t)b * NSPLIT + k) * JU + t];
      sv[bi][t] = s;
    }
  }
  __syncthreads();
  if (t < 2 * US) {
    int bi = t >> 4, u = t & 15;
    float m = 0.0f;
#pragma unroll
    for (int j = 0; j < NU; ++j) {
      float q = sv[bi][j * US + u];
      m += q * q;
    }
    fac[bi][u] = sqrtf(m) / (BETAC + m);
  }
  __syncthreads();
  if (t < JU) {
#pragma unroll
    for (int bi = 0; bi < 2; ++bi) {
      int b = b0 + blockIdx.y * 2 + bi;
      float val = sv[bi][t] * fac[bi][t & 15];
      vT[(size_t)t * B + b] = f2bf(val);
      if (out) out[(size_t)b * JU + t] = val;
    }
  }
}

// ---------------------------------------------------------------------------
// uc_kernel = b_update + tail-fused softmax_scale:
// GEMM: R[ki,ju] = sum_b xT[ki,b]*vT[ju,b] (K=b, split NBS=2);
// bp[p][j][i] = (1/B) sum_u Wr[ki][ju]*R (16-lane shfl reduce).
// Tail: one global counter (576); 160 designated blocks each produce one
// Wc row: softmax_i(sum_p bp[.,j,.]) folded into Wc[ju] = bf16(Wt[ju]*c).
// Grid: (144, 2, 2) x 256 = 576 blocks, all co-resident (<=4-5 blocks/CU).
// ---------------------------------------------------------------------------
__global__ __launch_bounds__(256) void uc_kernel(
    const unsigned short* __restrict__ xT, const unsigned short* __restrict__ vT,
    const float* __restrict__ Wr, float* __restrict__ bp,
    const unsigned short* __restrict__ Wt, unsigned short* __restrict__ Wc,
    int* __restrict__ cnt) {
  int k = blockIdx.x / 18;
  int i0 = (blockIdx.x - k * 18) * 64;
  int bs = blockIdx.y;
  int j0 = blockIdx.z * 80;
  size_t ki0 = (size_t)k * IC + i0;
  int t = threadIdx.x;
  int w = t >> 6, lane = t & 63, col = lane & 15, quad = lane >> 4;
  __shared__ unsigned short xs[2][64 * 40];
  __shared__ unsigned short vs[2][80 * 40];
  __shared__ float csm[IC];
  __shared__ float red[256];
  int xrow = t >> 2, xc = (t & 3) * 8;
  int mrow0 = t >> 2, mrow1 = 64 + (t >> 2);
  int mc = (t & 3) * 8;
  uint4 xv, m0, m1;
  auto prefetch = [&](int c0) {
    xv = *(const uint4*)&xT[(ki0 + xrow) * B + c0 + xc];
    m0 = *(const uint4*)&vT[(size_t)(j0 + mrow0) * B + c0 + mc];
    if (t < 64) m1 = *(const uint4*)&vT[(size_t)(j0 + mrow1) * B + c0 + mc];
  };
  auto commit = [&](int pb) {
    *(uint4*)&xs[pb][xrow * 40 + xc] = xv;
    *(uint4*)&vs[pb][mrow0 * 40 + mc] = m0;
    if (t < 64) *(uint4*)&vs[pb][mrow1 * 40 + mc] = m1;
  };
  floatx4 acc[5];
#pragma unroll
  for (int jt = 0; jt < 5; ++jt) acc[jt] = (floatx4){0.f, 0.f, 0.f, 0.f};
  const int nsteps = (B / NBS) >> 5;  // 8
  prefetch(bs * (B / NBS));
  commit(0);
  prefetch(bs * (B / NBS) + 32);
  for (int s = 0; s < nsteps; ++s) {
    __syncthreads();
    if (s + 1 < nsteps) commit((s + 1) & 1);
    if (s + 2 < nsteps) prefetch(bs * (B / NBS) + (s + 2) * 32);
    bf16x8 a = *(bf16x8*)&xs[s & 1][(w * 16 + col) * 40 + quad * 8];
#pragma unroll
    for (int jt = 0; jt < 5; ++jt) {
      bf16x8 bb = *(bf16x8*)&vs[s & 1][(jt * 16 + col) * 40 + quad * 8];
      acc[jt] = __builtin_amdgcn_mfma_f32_16x16x32_bf16(a, bb, acc[jt], 0, 0, 0);
    }
  }
  int p = k * NBS + bs;
  int jb = blockIdx.z * 5;            // bp j offset
#pragma unroll
  for (int jt = 0; jt < 5; ++jt) {
#pragma unroll
    for (int r = 0; r < 4; ++r) {
      int i = i0 + w * 16 + quad * 4 + r;
      float wv = Wr[((size_t)k * IC + i) * JU + j0 + jt * 16 + col];
      float pr = wv * acc[jt][r];
      pr += __shfl_xor(pr, 1);
      pr += __shfl_xor(pr, 2);
      pr += __shfl_xor(pr, 4);
      pr += __shfl_xor(pr, 8);
      if (col == 0)
        bp[(size_t)p * (IC * NU) + (jb + jt) * IC + i] = pr * (1.0f / (float)B);
    }
  }

  // ---- tail: signal; 160 designated blocks each produce one Wc row ----
  __syncthreads();
  if (t == 0) {
    __threadfence();
    __hip_atomic_fetch_add(cnt, 1, __ATOMIC_RELAXED, __HIP_MEMORY_SCOPE_AGENT);
  }
  int ju = -1;
  if (blockIdx.z == 0) {
    if (blockIdx.y == 0) ju = blockIdx.x;                       // 0..143
    else if (blockIdx.x < 16) ju = 144 + blockIdx.x;            // 144..159
  }
  if (ju < 0) return;
  if (t == 0) {
    while (__hip_atomic_load(cnt, __ATOMIC_RELAXED, __HIP_MEMORY_SCOPE_AGENT) <
           144 * 2 * 2)
      __builtin_amdgcn_s_sleep(1);
    __threadfence();
  }
  __syncthreads();
  const int j = ju >> 4;
  for (int i = t; i < IC; i += 256) {
    float s = 0.0f;
#pragma unroll
    for (int pp = 0; pp < NP; ++pp) s += bp[(size_t)pp * (IC * NU) + j * IC + i];
    csm[i] = s;
  }
  __syncthreads();
  float m = -1e30f;
  for (int i = t; i < IC; i += 256) m = fmaxf(m, csm[i]);
  red[t] = m;
  __syncthreads();
  for (int o = 128; o > 0; o >>= 1) {
    if (t < o) red[t] = fmaxf(red[t], red[t + o]);
    __syncthreads();
  }
  float mx = red[0];
  __syncthreads();
  float sm = 0.0f;
  for (int i = t; i < IC; i += 256) {
    float e = __expf(csm[i] - mx);
    csm[i] = e;
    sm += e;
  }
  red[t] = sm;
  __syncthreads();
  for (int o = 128; o > 0; o >>= 1) {
    if (t < o) red[t] += red[t + o];
    __syncthreads();
  }
  float inv = 1.0f / red[0];
  // write one Wc row (9216 bf16 = 1152 x uint4), fully coalesced
  for (int q = t; q < KI / 8; q += 256) {
    int ki = q * 8;
    int i = ki % IC;            // chunk never straddles k (IC % 8 == 0)
    uint4 wv = *(const uint4*)&Wt[(size_t)ju * KI + ki];
    float4 cA = make_float4(csm[i] * inv, csm[i + 1] * inv,
                            csm[i + 2] * inv, csm[i + 3] * inv);
    float4 cB = make_float4(csm[i + 4] * inv, csm[i + 5] * inv,
                            csm[i + 6] * inv, csm[i + 7] * inv);
    *(uint4*)&Wc[(size_t)ju * KI + ki] = scale8(wv, cA, cB);
  }
}

// ---------------------------------------------------------------------------
extern "C" void kernel_launch(void* const* d_in, const int* in_sizes, int n_in,
                              void* d_out, int out_size, void* d_ws,
                              size_t ws_size, hipStream_t stream) {
  const float* x = (const float*)d_in[0];   // (512, 8, 1152)
  const float* W = (const float*)d_in[1];   // (1152, 10, 16, 8)
  float* out = (float*)d_out;               // (512, 10, 16)

  // workspace layout (~42 MB; harness provides ~268 MB)
  char* pws = (char*)d_ws;
  float* bp = (float*)pws;                     pws += (size_t)NP * IC * NU * 4;
  float* sp = (float*)pws;                     pws += (size_t)NSPLIT * B * JU * 4;
  float* Wr = (float*)pws;                     pws += (size_t)KI * JU * 4;
  unsigned short* xb = (unsigned short*)pws;   pws += (size_t)B * KI * 2;
  unsigned short* xT = (unsigned short*)pws;   pws += (size_t)KI * B * 2;
  unsigned short* Wt = (unsigned short*)pws;   pws += (size_t)JU * KI * 2;
  unsigned short* Wc = (unsigned short*)pws;   pws += (size_t)JU * KI * 2;
  unsigned short* vT = (unsigned short*)pws;   pws += (size_t)JU * B * 2;
  int* cnts = (int*)pws;   // [0..23]: GS per-iter x 8 b-tiles; [24..25]: UC

  prep_kernel<<<1152 + 144, 256, 0, stream>>>(x, W, xb, xT, Wt, Wc, Wr, cnts);

  for (int it = 0; it < 3; ++it) {
    gs_kernel<<<dim3(8, NSPLIT, 2), 256, 0, stream>>>(
        xb, Wc, sp, vT, (it == 2) ? out : nullptr, cnts + it * 8);
    if (it < 2)
      uc_kernel<<<dim3(144, NBS, 2), 256, 0, stream>>>(
          xT, vT, Wr, bp, Wt, Wc, cnts + 24 + it);
  }
}

// Round 8
// 160.087 us; speedup vs baseline: 2.3203x; 2.3203x over previous
//
#include <hip/hip_runtime.h>
#include <hip/hip_bf16.h>
#include <math.h>

#define B    512
#define INU  8
#define IC   1152
#define NU   10
#define US   16
#define JU   160            // NU*US
#define KI   9216           // INU*IC
#define BETAC 1.45f
#define NSPLIT 32           // s_gemm k-chunks; KC = KI/NSPLIT
#define KC 288              // 9 MFMA steps of 32
#define NBS 2               // b_update batch splits (256 each)
#define NP  16              // bp p-slices = 8 ki-groups * NBS

typedef __attribute__((ext_vector_type(8))) __bf16 bf16x8;
typedef __attribute__((ext_vector_type(4))) float floatx4;

static __device__ __forceinline__ unsigned short f2bf(float f) {
  unsigned u = __builtin_bit_cast(unsigned, f);
  u = (u + 0x7fffu + ((u >> 16) & 1u)) >> 16;   // RNE
  return (unsigned short)u;
}
static __device__ __forceinline__ float bf2f(unsigned short h) {
  return __builtin_bit_cast(float, ((unsigned)h) << 16);
}
// 8 bf16 * 8 fp32 scale -> 8 bf16 (packed RNE converts)
static __device__ __forceinline__ uint4 scale8(uint4 wv, float4 cA, float4 cB) {
  union { uint4 u; unsigned short s[8]; } in;
  in.u = wv;
  union { uint4 u; __hip_bfloat162 h[4]; } o;
  o.h[0] = __float22bfloat162_rn(make_float2(bf2f(in.s[0]) * cA.x, bf2f(in.s[1]) * cA.y));
  o.h[1] = __float22bfloat162_rn(make_float2(bf2f(in.s[2]) * cA.z, bf2f(in.s[3]) * cA.w));
  o.h[2] = __float22bfloat162_rn(make_float2(bf2f(in.s[4]) * cB.x, bf2f(in.s[5]) * cB.y));
  o.h[3] = __float22bfloat162_rn(make_float2(bf2f(in.s[6]) * cB.z, bf2f(in.s[7]) * cB.w));
  return o.u;
}

// ---------------------------------------------------------------------------
// prep (one-time): blocks [0,1152): x -> xb bf16 [b][ki] + xT bf16 [ki][b],
// now fully vectorized: float4 x-loads, ushort4 xb-stores, bf16-packed LDS
// transpose (identical f2bf values -> bit-identical outputs vs round 4).
// blocks [1152,1296): W LDS-tiled (float4 loads, ts stride 324 for 16B
// alignment) -> Wt bf16 [ju][ki] + Wc = Wt*(1/IC) + Wr fp32 [ki][ju].
// ---------------------------------------------------------------------------
__global__ __launch_bounds__(256) void prep_kernel(
    const float* __restrict__ x, const float* __restrict__ W,
    unsigned short* __restrict__ xb, unsigned short* __restrict__ xT,
    unsigned short* __restrict__ Wt, unsigned short* __restrict__ Wc,
    float* __restrict__ Wr) {
  __shared__ float ts[32 * 324];    // 41.5 KB (x-part aliases first 9 KB)
  unsigned short* tsb = (unsigned short*)ts;   // [64][70] bf16 (pad 6)
  int id = blockIdx.x;
  int t = threadIdx.x;
  if (id < 1152) {
    int k0 = (id % 144) * 64;
    int b0 = (id / 144) * 64;
#pragma unroll
    for (int r = 0; r < 4; ++r) {
      int idx = t + 256 * r;          // 0..1023 float4s
      int br = idx >> 4, kc = (idx & 15) * 4;
      float4 v = *(const float4*)&x[(size_t)(b0 + br) * KI + k0 + kc];
      ushort4 h;
      h.x = f2bf(v.x); h.y = f2bf(v.y); h.z = f2bf(v.z); h.w = f2bf(v.w);
      *(ushort4*)&xb[(size_t)(b0 + br) * KI + k0 + kc] = h;
      *(unsigned*)&tsb[br * 70 + kc] = (unsigned)h.x | ((unsigned)h.y << 16);
      *(unsigned*)&tsb[br * 70 + kc + 2] = (unsigned)h.z | ((unsigned)h.w << 16);
    }
    __syncthreads();
#pragma unroll
    for (int r = 0; r < 8; ++r) {
      int idx = t + 256 * r;            // 0..2047
      int kr = idx >> 5, bc = (idx & 31) * 2;
      unsigned lo = tsb[bc * 70 + kr];
      unsigned hi = tsb[(bc + 1) * 70 + kr];
      *(unsigned*)&xT[(size_t)(k0 + kr) * B + b0 + bc] = lo | (hi << 16);
    }
  } else {
    int wid = id - 1152;              // 0..143
    int i0 = (wid >> 2) * 32;         // 36 i-chunks
    int c0 = (wid & 3) * 320;         // 4 c-chunks of W's 1280-wide rows
#pragma unroll
    for (int r = 0; r < 10; ++r) {
      int q = t + 256 * r;            // < 2560 float4
      int il = q / 80, c = (q - il * 80) * 4;
      *(float4*)&ts[il * 324 + c] =
          *(const float4*)&W[(size_t)(i0 + il) * 1280 + c0 + c];
    }
    __syncthreads();
    {
      const float cinv = 1.0f / (float)IC;
      int il2 = (t & 15) * 2;
      for (int p = (t >> 4); p < 320; p += 16) {
        int c = c0 + p;
        int ju = c >> 3, k = c & 7;
        unsigned lo = f2bf(ts[il2 * 324 + p]);
        unsigned hi = f2bf(ts[(il2 + 1) * 324 + p]);
        *(unsigned*)&Wt[(size_t)ju * KI + k * IC + i0 + il2] = lo | (hi << 16);
        unsigned lo2 = f2bf(bf2f((unsigned short)lo) * cinv);
        unsigned hi2 = f2bf(bf2f((unsigned short)hi) * cinv);
        *(unsigned*)&Wc[(size_t)ju * KI + k * IC + i0 + il2] = lo2 | (hi2 << 16);
      }
    }
    int ju0 = c0 >> 3;
    for (int q = t; q < 8 * 32 * 40; q += 256) {
      int k = q / 1280;
      int il = (q / 40) & 31;
      int jl = q - (q / 40) * 40;
      Wr[((size_t)k * IC + i0 + il) * JU + ju0 + jl] = ts[il * 324 + jl * 8 + k];
    }
  }
}

// ---------------------------------------------------------------------------
// s_gemm (round-4 structure, 3-deep register prefetch): each global load now
// stays in flight ~2 loop iterations (~600-800 cyc, covering HBM latency)
// instead of 1. Named reg sets A (prologue) / B / C — static, no spills.
// sp[b][y][j0+..] = sum_{ki in chunk y} xb * Wc.
// Grid: (8 b-tiles, 32 k-chunks, 2 j-halves) x 256 = 512 blocks = 2/CU.
// ---------------------------------------------------------------------------
__global__ __launch_bounds__(256) void s_gemm_mfma(
    const unsigned short* __restrict__ xb, const unsigned short* __restrict__ Wc,
    float* __restrict__ sp) {
  int b0 = blockIdx.x * 64;
  int kbase = blockIdx.y * KC;
  int j0 = blockIdx.z * 80;           // j-half row offset
  int t = threadIdx.x;
  int w = t >> 6, lane = t & 63, col = lane & 15, quad = lane >> 4;
  __shared__ unsigned short xs[2][64 * 40];   // pad 40: <=2-way (free)
  __shared__ unsigned short ms[2][80 * 40];

  int xrow = t >> 2, xc = (t & 3) * 8;
  int mrow0 = t >> 2, mrow1 = 64 + (t >> 2);  // rows 64..79 by t<64
  int mc = (t & 3) * 8;

  uint4 xvA, m0A, m1A, xvB, m0B, m1B, xvC, m0C, m1C;
#define S_LOAD(X, M0, M1, kk)                                              \
  do {                                                                     \
    X = *(const uint4*)&xb[(size_t)(b0 + xrow) * KI + (kk) + xc];          \
    M0 = *(const uint4*)&Wc[(size_t)(j0 + mrow0) * KI + (kk) + mc];        \
    if (t < 64) M1 = *(const uint4*)&Wc[(size_t)(j0 + mrow1) * KI + (kk) + mc]; \
  } while (0)
#define S_COMMIT(X, M0, M1, pb)                                            \
  do {                                                                     \
    *(uint4*)&xs[pb][xrow * 40 + xc] = X;                                  \
    *(uint4*)&ms[pb][mrow0 * 40 + mc] = M0;                                \
    if (t < 64) *(uint4*)&ms[pb][mrow1 * 40 + mc] = M1;                    \
  } while (0)

  floatx4 acc[5];
#pragma unroll
  for (int jt = 0; jt < 5; ++jt) acc[jt] = (floatx4){0.f, 0.f, 0.f, 0.f};
  const int nsteps = KC >> 5;  // 9
  S_LOAD(xvA, m0A, m1A, kbase);
  S_COMMIT(xvA, m0A, m1A, 0);
  S_LOAD(xvB, m0B, m1B, kbase + 32);        // step 1
  S_LOAD(xvC, m0C, m1C, kbase + 64);        // step 2
#pragma unroll
  for (int s = 0; s < nsteps; ++s) {
    __syncthreads();                        // buf[s&1] complete for all waves
    if ((s & 1) == 0) {                     // odd steps live in set B
      if (s + 1 < nsteps) S_COMMIT(xvB, m0B, m1B, (s + 1) & 1);
      if (s + 3 < nsteps) S_LOAD(xvB, m0B, m1B, kbase + (s + 3) * 32);
    } else {                                // even steps (>=2) live in set C
      if (s + 1 < nsteps) S_COMMIT(xvC, m0C, m1C, (s + 1) & 1);
      if (s + 3 < nsteps) S_LOAD(xvC, m0C, m1C, kbase + (s + 3) * 32);
    }
    bf16x8 a = *(bf16x8*)&xs[s & 1][(w * 16 + col) * 40 + quad * 8];
#pragma unroll
    for (int jt = 0; jt < 5; ++jt) {
      bf16x8 bb = *(bf16x8*)&ms[s & 1][(jt * 16 + col) * 40 + quad * 8];
      acc[jt] = __builtin_amdgcn_mfma_f32_16x16x32_bf16(a, bb, acc[jt], 0, 0, 0);
    }
  }
#undef S_LOAD
#undef S_COMMIT
#pragma unroll
  for (int jt = 0; jt < 5; ++jt)
#pragma unroll
    for (int r = 0; r < 4; ++r) {
      int b = b0 + w * 16 + quad * 4 + r;
      sp[((size_t)b * NSPLIT + blockIdx.y) * JU + j0 + jt * 16 + col] = acc[jt][r];
    }
}

// ---------------------------------------------------------------------------
// squash: s[b][ju] = sum_y sp[b][y][ju] (contiguous 20.5 KB per block);
// msq over j (axis=1 quirk, faithful); v -> vT bf16 [ju][b]; out fp32 on
// last iter. Grid: 512 x 192.
// ---------------------------------------------------------------------------
__global__ __launch_bounds__(192) void squash_kernel(
    const float* __restrict__ sp, unsigned short* __restrict__ vT,
    float* __restrict__ out) {
  int b = blockIdx.x;
  int t = threadIdx.x;
  __shared__ float sv[JU];
  __shared__ float fac[US];
  float s = 0.0f;
  if (t < JU) {
#pragma unroll
    for (int k = 0; k < NSPLIT; ++k) s += sp[((size_t)b * NSPLIT + k) * JU + t];
    sv[t] = s;
  }
  __syncthreads();
  if (t < US) {
    float m = 0.0f;
#pragma unroll
    for (int j = 0; j < NU; ++j) {
      float q = sv[j * US + t];
      m += q * q;
    }
    fac[t] = sqrtf(m) / (BETAC + m);
  }
  __syncthreads();
  if (t < JU) {
    float val = s * fac[t & 15];
    vT[(size_t)t * B + b] = f2bf(val);
    if (out) out[(size_t)b * JU + t] = val;
  }
}

// ---------------------------------------------------------------------------
// b_update (round-4 structure, 3-deep register prefetch):
// R[ki,ju] = sum_b xT[ki,b]*vT[ju,b] (K=b, split NBS=2);
// bp[p][j][i] = (1/B) sum_u Wr[ki][ju]*R (16-lane shfl reduce, u=lane&15).
// Grid: (144 ki-tiles, 2 b-halves, 2 j-halves) x 256 = 576 blocks.
// Deterministic slice writes, no atomics, no fences.
// ---------------------------------------------------------------------------
__global__ __launch_bounds__(256) void b_update_mfma(
    const unsigned short* __restrict__ xT, const unsigned short* __restrict__ vT,
    const float* __restrict__ Wr, float* __restrict__ bp) {
  int k = blockIdx.x / 18;
  int i0 = (blockIdx.x - k * 18) * 64;
  int bs = blockIdx.y;
  int j0 = blockIdx.z * 80;
  size_t ki0 = (size_t)k * IC + i0;
  int t = threadIdx.x;
  int w = t >> 6, lane = t & 63, col = lane & 15, quad = lane >> 4;
  __shared__ unsigned short xs[2][64 * 40];
  __shared__ unsigned short vs[2][80 * 40];
  int xrow = t >> 2, xc = (t & 3) * 8;
  int mrow0 = t >> 2, mrow1 = 64 + (t >> 2);
  int mc = (t & 3) * 8;
  const int cb = bs * (B / NBS);

  uint4 xvA, m0A, m1A, xvB, m0B, m1B, xvC, m0C, m1C;
#define U_LOAD(X, M0, M1, cc)                                              \
  do {                                                                     \
    X = *(const uint4*)&xT[(ki0 + xrow) * B + (cc) + xc];                  \
    M0 = *(const uint4*)&vT[(size_t)(j0 + mrow0) * B + (cc) + mc];         \
    if (t < 64) M1 = *(const uint4*)&vT[(size_t)(j0 + mrow1) * B + (cc) + mc]; \
  } while (0)
#define U_COMMIT(X, M0, M1, pb)                                            \
  do {                                                                     \
    *(uint4*)&xs[pb][xrow * 40 + xc] = X;                                  \
    *(uint4*)&vs[pb][mrow0 * 40 + mc] = M0;                                \
    if (t < 64) *(uint4*)&vs[pb][mrow1 * 40 + mc] = M1;                    \
  } while (0)

  floatx4 acc[5];
#pragma unroll
  for (int jt = 0; jt < 5; ++jt) acc[jt] = (floatx4){0.f, 0.f, 0.f, 0.f};
  const int nsteps = (B / NBS) >> 5;  // 8
  U_LOAD(xvA, m0A, m1A, cb);
  U_COMMIT(xvA, m0A, m1A, 0);
  U_LOAD(xvB, m0B, m1B, cb + 32);
  U_LOAD(xvC, m0C, m1C, cb + 64);
#pragma unroll
  for (int s = 0; s < nsteps; ++s) {
    __syncthreads();
    if ((s & 1) == 0) {
      if (s + 1 < nsteps) U_COMMIT(xvB, m0B, m1B, (s + 1) & 1);
      if (s + 3 < nsteps) U_LOAD(xvB, m0B, m1B, cb + (s + 3) * 32);
    } else {
      if (s + 1 < nsteps) U_COMMIT(xvC, m0C, m1C, (s + 1) & 1);
      if (s + 3 < nsteps) U_LOAD(xvC, m0C, m1C, cb + (s + 3) * 32);
    }
    bf16x8 a = *(bf16x8*)&xs[s & 1][(w * 16 + col) * 40 + quad * 8];
#pragma unroll
    for (int jt = 0; jt < 5; ++jt) {
      bf16x8 bb = *(bf16x8*)&vs[s & 1][(jt * 16 + col) * 40 + quad * 8];
      acc[jt] = __builtin_amdgcn_mfma_f32_16x16x32_bf16(a, bb, acc[jt], 0, 0, 0);
    }
  }
#undef U_LOAD
#undef U_COMMIT
  int p = k * NBS + bs;
  int jb = blockIdx.z * 5;            // bp j offset
#pragma unroll
  for (int jt = 0; jt < 5; ++jt) {
#pragma unroll
    for (int r = 0; r < 4; ++r) {
      int i = i0 + w * 16 + quad * 4 + r;
      float wv = Wr[((size_t)k * IC + i) * JU + j0 + jt * 16 + col];
      float pr = wv * acc[jt][r];
      pr += __shfl_xor(pr, 1);
      pr += __shfl_xor(pr, 2);
      pr += __shfl_xor(pr, 4);
      pr += __shfl_xor(pr, 8);
      if (col == 0)
        bp[(size_t)p * (IC * NU) + (jb + jt) * IC + i] = pr * (1.0f / (float)B);
    }
  }
}

// ---------------------------------------------------------------------------
// softmax_scale: bij[j][i] = sum_p bp[p][j][i]; c[j][i] = softmax_i;
// then write Wc[ju][ki] = bf16(Wt[ju][ki] * c[j, i(ki)]) for the next
// routing iteration. One block per ju row (softmax recomputed redundantly
// per block — L2-hot bp reads; Wc row writes fully coalesced). Grid: 160x256.
// ---------------------------------------------------------------------------
__global__ __launch_bounds__(256) void softmax_scale_kernel(
    const float* __restrict__ bp, const unsigned short* __restrict__ Wt,
    unsigned short* __restrict__ Wc) {
  int ju = blockIdx.x;          // 0..159
  int j = ju >> 4;
  int t = threadIdx.x;
  __shared__ float c[IC];
  __shared__ float red[256];
  for (int i = t; i < IC; i += 256) {
    float s = 0.0f;
#pragma unroll
    for (int p = 0; p < NP; ++p) s += bp[(size_t)p * (IC * NU) + j * IC + i];
    c[i] = s;
  }
  __syncthreads();
  float m = -1e30f;
  for (int i = t; i < IC; i += 256) m = fmaxf(m, c[i]);
  red[t] = m;
  __syncthreads();
  for (int o = 128; o > 0; o >>= 1) {
    if (t < o) red[t] = fmaxf(red[t], red[t + o]);
    __syncthreads();
  }
  float mx = red[0];
  __syncthreads();
  float sm = 0.0f;
  for (int i = t; i < IC; i += 256) {
    float e = __expf(c[i] - mx);
    c[i] = e;
    sm += e;
  }
  red[t] = sm;
  __syncthreads();
  for (int o = 128; o > 0; o >>= 1) {
    if (t < o) red[t] += red[t + o];
    __syncthreads();
  }
  float inv = 1.0f / red[0];
  // write one Wc row (9216 bf16 = 1152 x uint4), fully coalesced
  for (int q = t; q < KI / 8; q += 256) {
    int ki = q * 8;
    int i = ki % IC;            // chunk never straddles k (IC % 8 == 0)
    uint4 wv = *(const uint4*)&Wt[(size_t)ju * KI + ki];
    float4 cA = make_float4(c[i] * inv, c[i + 1] * inv, c[i + 2] * inv, c[i + 3] * inv);
    float4 cB = make_float4(c[i + 4] * inv, c[i + 5] * inv, c[i + 6] * inv, c[i + 7] * inv);
    *(uint4*)&Wc[(size_t)ju * KI + ki] = scale8(wv, cA, cB);
  }
}

// ---------------------------------------------------------------------------
extern "C" void kernel_launch(void* const* d_in, const int* in_sizes, int n_in,
                              void* d_out, int out_size, void* d_ws,
                              size_t ws_size, hipStream_t stream) {
  const float* x = (const float*)d_in[0];   // (512, 8, 1152)
  const float* W = (const float*)d_in[1];   // (1152, 10, 16, 8)
  float* out = (float*)d_out;               // (512, 10, 16)

  // workspace layout (~42 MB; harness provides ~268 MB)
  char* pws = (char*)d_ws;
  float* bp = (float*)pws;                     pws += (size_t)NP * IC * NU * 4;
  float* sp = (float*)pws;                     pws += (size_t)NSPLIT * B * JU * 4;
  float* Wr = (float*)pws;                     pws += (size_t)KI * JU * 4;
  unsigned short* xb = (unsigned short*)pws;   pws += (size_t)B * KI * 2;
  unsigned short* xT = (unsigned short*)pws;   pws += (size_t)KI * B * 2;
  unsigned short* Wt = (unsigned short*)pws;   pws += (size_t)JU * KI * 2;
  unsigned short* Wc = (unsigned short*)pws;   pws += (size_t)JU * KI * 2;
  unsigned short* vT = (unsigned short*)pws;

  prep_kernel<<<1152 + 144, 256, 0, stream>>>(x, W, xb, xT, Wt, Wc, Wr);

  for (int it = 0; it < 3; ++it) {
    s_gemm_mfma<<<dim3(8, NSPLIT, 2), 256, 0, stream>>>(xb, Wc, sp);
    squash_kernel<<<B, 192, 0, stream>>>(sp, vT, (it == 2) ? out : nullptr);
    if (it < 2) {
      b_update_mfma<<<dim3(144, NBS, 2), 256, 0, stream>>>(xT, vT, Wr, bp);
      softmax_scale_kernel<<<160, 256, 0, stream>>>(bp, Wt, Wc);
    }
  }
}

// Round 9
// 157.902 us; speedup vs baseline: 2.3524x; 1.0138x over previous
//
#include <hip/hip_runtime.h>
#include <hip/hip_bf16.h>
#include <math.h>

#define B    512
#define INU  8
#define IC   1152
#define NU   10
#define US   16
#define JU   160            // NU*US
#define KI   9216           // INU*IC
#define BETAC 1.45f
#define NSPLIT 32           // s_gemm k-chunks; KC = KI/NSPLIT
#define KC 288              // 9 MFMA steps of 32
#define NBS 2               // b_update batch splits (256 each)
#define NP  16              // bp p-slices = 8 ki-groups * NBS

typedef __attribute__((ext_vector_type(8))) __bf16 bf16x8;
typedef __attribute__((ext_vector_type(4))) float floatx4;

static __device__ __forceinline__ unsigned short f2bf(float f) {
  unsigned u = __builtin_bit_cast(unsigned, f);
  u = (u + 0x7fffu + ((u >> 16) & 1u)) >> 16;   // RNE
  return (unsigned short)u;
}
static __device__ __forceinline__ float bf2f(unsigned short h) {
  return __builtin_bit_cast(float, ((unsigned)h) << 16);
}
// 8 bf16 * 8 fp32 scale -> 8 bf16 (packed RNE converts)
static __device__ __forceinline__ uint4 scale8(uint4 wv, float4 cA, float4 cB) {
  union { uint4 u; unsigned short s[8]; } in;
  in.u = wv;
  union { uint4 u; __hip_bfloat162 h[4]; } o;
  o.h[0] = __float22bfloat162_rn(make_float2(bf2f(in.s[0]) * cA.x, bf2f(in.s[1]) * cA.y));
  o.h[1] = __float22bfloat162_rn(make_float2(bf2f(in.s[2]) * cA.z, bf2f(in.s[3]) * cA.w));
  o.h[2] = __float22bfloat162_rn(make_float2(bf2f(in.s[4]) * cB.x, bf2f(in.s[5]) * cB.y));
  o.h[3] = __float22bfloat162_rn(make_float2(bf2f(in.s[6]) * cB.z, bf2f(in.s[7]) * cB.w));
  return o.u;
}

// ---------------------------------------------------------------------------
// prep (one-time, vectorized): blocks [0,1152): x -> xb bf16 [b][ki] + xT
// bf16 [ki][b]; float4 x-loads, ushort4 xb-stores, bf16-packed LDS transpose
// (identical f2bf values -> bit-identical outputs). blocks [1152,1296):
// W LDS-tiled (float4 loads, stride 324) -> Wt bf16 [ju][ki] (MFMA B layout)
// + Wc = Wt*(1/IC) (iteration-0 scaled weights) + Wr fp32 [ki][ju].
// ---------------------------------------------------------------------------
__global__ __launch_bounds__(256) void prep_kernel(
    const float* __restrict__ x, const float* __restrict__ W,
    unsigned short* __restrict__ xb, unsigned short* __restrict__ xT,
    unsigned short* __restrict__ Wt, unsigned short* __restrict__ Wc,
    float* __restrict__ Wr) {
  __shared__ float ts[32 * 324];    // 41.5 KB (x-part aliases first 9 KB)
  unsigned short* tsb = (unsigned short*)ts;   // [64][70] bf16 (pad 6)
  int id = blockIdx.x;
  int t = threadIdx.x;
  if (id < 1152) {
    int k0 = (id % 144) * 64;
    int b0 = (id / 144) * 64;
#pragma unroll
    for (int r = 0; r < 4; ++r) {
      int idx = t + 256 * r;          // 0..1023 float4s
      int br = idx >> 4, kc = (idx & 15) * 4;
      float4 v = *(const float4*)&x[(size_t)(b0 + br) * KI + k0 + kc];
      ushort4 h;
      h.x = f2bf(v.x); h.y = f2bf(v.y); h.z = f2bf(v.z); h.w = f2bf(v.w);
      *(ushort4*)&xb[(size_t)(b0 + br) * KI + k0 + kc] = h;
      *(unsigned*)&tsb[br * 70 + kc] = (unsigned)h.x | ((unsigned)h.y << 16);
      *(unsigned*)&tsb[br * 70 + kc + 2] = (unsigned)h.z | ((unsigned)h.w << 16);
    }
    __syncthreads();
#pragma unroll
    for (int r = 0; r < 8; ++r) {
      int idx = t + 256 * r;            // 0..2047
      int kr = idx >> 5, bc = (idx & 31) * 2;
      unsigned lo = tsb[bc * 70 + kr];
      unsigned hi = tsb[(bc + 1) * 70 + kr];
      *(unsigned*)&xT[(size_t)(k0 + kr) * B + b0 + bc] = lo | (hi << 16);
    }
  } else {
    int wid = id - 1152;              // 0..143
    int i0 = (wid >> 2) * 32;         // 36 i-chunks
    int c0 = (wid & 3) * 320;         // 4 c-chunks of W's 1280-wide rows
#pragma unroll
    for (int r = 0; r < 10; ++r) {
      int q = t + 256 * r;            // < 2560 float4
      int il = q / 80, c = (q - il * 80) * 4;
      *(float4*)&ts[il * 324 + c] =
          *(const float4*)&W[(size_t)(i0 + il) * 1280 + c0 + c];
    }
    __syncthreads();
    {
      const float cinv = 1.0f / (float)IC;
      int il2 = (t & 15) * 2;
      for (int p = (t >> 4); p < 320; p += 16) {
        int c = c0 + p;
        int ju = c >> 3, k = c & 7;
        unsigned lo = f2bf(ts[il2 * 324 + p]);
        unsigned hi = f2bf(ts[(il2 + 1) * 324 + p]);
        *(unsigned*)&Wt[(size_t)ju * KI + k * IC + i0 + il2] = lo | (hi << 16);
        unsigned lo2 = f2bf(bf2f((unsigned short)lo) * cinv);
        unsigned hi2 = f2bf(bf2f((unsigned short)hi) * cinv);
        *(unsigned*)&Wc[(size_t)ju * KI + k * IC + i0 + il2] = lo2 | (hi2 << 16);
      }
    }
    int ju0 = c0 >> 3;
    for (int q = t; q < 8 * 32 * 40; q += 256) {
      int k = q / 1280;
      int il = (q / 40) & 31;
      int jl = q - (q / 40) * 40;
      Wr[((size_t)k * IC + i0 + il) * JU + ju0 + jl] = ts[il * 324 + jl * 8 + k];
    }
  }
}

// ---------------------------------------------------------------------------
// s_gemm (round-4 exact structure: LDS double-buffered, 2-deep prefetch,
// 1 barrier/step — the measured-best config):
// sp[b][y][j0+..] = sum_{ki in chunk y} xb * Wc.
// Grid: (8 b-tiles, 32 k-chunks, 2 j-halves) x 256 = 512 blocks = 2/CU.
// ---------------------------------------------------------------------------
__global__ __launch_bounds__(256) void s_gemm_mfma(
    const unsigned short* __restrict__ xb, const unsigned short* __restrict__ Wc,
    float* __restrict__ sp) {
  int b0 = blockIdx.x * 64;
  int kbase = blockIdx.y * KC;
  int j0 = blockIdx.z * 80;           // j-half row offset
  int t = threadIdx.x;
  int w = t >> 6, lane = t & 63, col = lane & 15, quad = lane >> 4;
  __shared__ unsigned short xs[2][64 * 40];   // pad 40: <=2-way (free)
  __shared__ unsigned short ms[2][80 * 40];

  int xrow = t >> 2, xc = (t & 3) * 8;
  int mrow0 = t >> 2, mrow1 = 64 + (t >> 2);  // rows 64..79 by t<64
  int mc = (t & 3) * 8;

  uint4 xv, m0, m1;
  auto prefetch = [&](int k0) {
    xv = *(const uint4*)&xb[(size_t)(b0 + xrow) * KI + k0 + xc];
    m0 = *(const uint4*)&Wc[(size_t)(j0 + mrow0) * KI + k0 + mc];
    if (t < 64) m1 = *(const uint4*)&Wc[(size_t)(j0 + mrow1) * KI + k0 + mc];
  };
  auto commit = [&](int pb) {
    *(uint4*)&xs[pb][xrow * 40 + xc] = xv;
    *(uint4*)&ms[pb][mrow0 * 40 + mc] = m0;
    if (t < 64) *(uint4*)&ms[pb][mrow1 * 40 + mc] = m1;
  };
  floatx4 acc[5];
#pragma unroll
  for (int jt = 0; jt < 5; ++jt) acc[jt] = (floatx4){0.f, 0.f, 0.f, 0.f};
  const int nsteps = KC >> 5;  // 9
  prefetch(kbase);
  commit(0);
  prefetch(kbase + 32);
  for (int s = 0; s < nsteps; ++s) {
    __syncthreads();                       // buf[s&1] complete for all waves
    if (s + 1 < nsteps) commit((s + 1) & 1);
    if (s + 2 < nsteps) prefetch(kbase + (s + 2) * 32);
    bf16x8 a = *(bf16x8*)&xs[s & 1][(w * 16 + col) * 40 + quad * 8];
#pragma unroll
    for (int jt = 0; jt < 5; ++jt) {
      bf16x8 bb = *(bf16x8*)&ms[s & 1][(jt * 16 + col) * 40 + quad * 8];
      acc[jt] = __builtin_amdgcn_mfma_f32_16x16x32_bf16(a, bb, acc[jt], 0, 0, 0);
    }
  }
#pragma unroll
  for (int jt = 0; jt < 5; ++jt)
#pragma unroll
    for (int r = 0; r < 4; ++r) {
      int b = b0 + w * 16 + quad * 4 + r;
      sp[((size_t)b * NSPLIT + blockIdx.y) * JU + j0 + jt * 16 + col] = acc[jt][r];
    }
}

// ---------------------------------------------------------------------------
// squash: s[b][ju] = sum_y sp[b][y][ju] (contiguous 20.5 KB per block);
// msq over j (axis=1 quirk, faithful); v -> vT bf16 [ju][b]; out fp32 on
// last iter. Grid: 512 x 192.
// ---------------------------------------------------------------------------
__global__ __launch_bounds__(192) void squash_kernel(
    const float* __restrict__ sp, unsigned short* __restrict__ vT,
    float* __restrict__ out) {
  int b = blockIdx.x;
  int t = threadIdx.x;
  __shared__ float sv[JU];
  __shared__ float fac[US];
  float s = 0.0f;
  if (t < JU) {
#pragma unroll
    for (int k = 0; k < NSPLIT; ++k) s += sp[((size_t)b * NSPLIT + k) * JU + t];
    sv[t] = s;
  }
  __syncthreads();
  if (t < US) {
    float m = 0.0f;
#pragma unroll
    for (int j = 0; j < NU; ++j) {
      float q = sv[j * US + t];
      m += q * q;
    }
    fac[t] = sqrtf(m) / (BETAC + m);
  }
  __syncthreads();
  if (t < JU) {
    float val = s * fac[t & 15];
    vT[(size_t)t * B + b] = f2bf(val);
    if (out) out[(size_t)b * JU + t] = val;
  }
}

// ---------------------------------------------------------------------------
// b_update (round-4 exact structure):
// R[ki,ju] = sum_b xT[ki,b]*vT[ju,b] (K=b, split NBS=2);
// bp[p][j][i] = (1/B) sum_u Wr[ki][ju]*R (16-lane shfl reduce, u=lane&15).
// Grid: (144 ki-tiles, 2 b-halves, 2 j-halves) x 256 = 576 blocks.
// Deterministic slice writes, no atomics, no fences.
// ---------------------------------------------------------------------------
__global__ __launch_bounds__(256) void b_update_mfma(
    const unsigned short* __restrict__ xT, const unsigned short* __restrict__ vT,
    const float* __restrict__ Wr, float* __restrict__ bp) {
  int k = blockIdx.x / 18;
  int i0 = (blockIdx.x - k * 18) * 64;
  int bs = blockIdx.y;
  int j0 = blockIdx.z * 80;
  size_t ki0 = (size_t)k * IC + i0;
  int t = threadIdx.x;
  int w = t >> 6, lane = t & 63, col = lane & 15, quad = lane >> 4;
  __shared__ unsigned short xs[2][64 * 40];
  __shared__ unsigned short vs[2][80 * 40];
  int xrow = t >> 2, xc = (t & 3) * 8;
  int mrow0 = t >> 2, mrow1 = 64 + (t >> 2);
  int mc = (t & 3) * 8;
  uint4 xv, m0, m1;
  auto prefetch = [&](int c0) {
    xv = *(const uint4*)&xT[(ki0 + xrow) * B + c0 + xc];
    m0 = *(const uint4*)&vT[(size_t)(j0 + mrow0) * B + c0 + mc];
    if (t < 64) m1 = *(const uint4*)&vT[(size_t)(j0 + mrow1) * B + c0 + mc];
  };
  auto commit = [&](int pb) {
    *(uint4*)&xs[pb][xrow * 40 + xc] = xv;
    *(uint4*)&vs[pb][mrow0 * 40 + mc] = m0;
    if (t < 64) *(uint4*)&vs[pb][mrow1 * 40 + mc] = m1;
  };
  floatx4 acc[5];
#pragma unroll
  for (int jt = 0; jt < 5; ++jt) acc[jt] = (floatx4){0.f, 0.f, 0.f, 0.f};
  const int nsteps = (B / NBS) >> 5;  // 8
  prefetch(bs * (B / NBS));
  commit(0);
  prefetch(bs * (B / NBS) + 32);
  for (int s = 0; s < nsteps; ++s) {
    __syncthreads();
    if (s + 1 < nsteps) commit((s + 1) & 1);
    if (s + 2 < nsteps) prefetch(bs * (B / NBS) + (s + 2) * 32);
    bf16x8 a = *(bf16x8*)&xs[s & 1][(w * 16 + col) * 40 + quad * 8];
#pragma unroll
    for (int jt = 0; jt < 5; ++jt) {
      bf16x8 bb = *(bf16x8*)&vs[s & 1][(jt * 16 + col) * 40 + quad * 8];
      acc[jt] = __builtin_amdgcn_mfma_f32_16x16x32_bf16(a, bb, acc[jt], 0, 0, 0);
    }
  }
  int p = k * NBS + bs;
  int jb = blockIdx.z * 5;            // bp j offset
#pragma unroll
  for (int jt = 0; jt < 5; ++jt) {
#pragma unroll
    for (int r = 0; r < 4; ++r) {
      int i = i0 + w * 16 + quad * 4 + r;
      float wv = Wr[((size_t)k * IC + i) * JU + j0 + jt * 16 + col];
      float pr = wv * acc[jt][r];
      pr += __shfl_xor(pr, 1);
      pr += __shfl_xor(pr, 2);
      pr += __shfl_xor(pr, 4);
      pr += __shfl_xor(pr, 8);
      if (col == 0)
        bp[(size_t)p * (IC * NU) + (jb + jt) * IC + i] = pr * (1.0f / (float)B);
    }
  }
}

// ---------------------------------------------------------------------------
// softmax_scale: bij[j][i] = sum_p bp[p][j][i]; c[j][i] = softmax_i;
// then write Wc[ju][ki] = bf16(Wt[ju][ki] * c[j, i(ki)]) for the next
// routing iteration. One block per ju row (softmax recomputed redundantly
// per block — L2-hot bp reads; Wc row writes fully coalesced). Grid: 160x256.
// ---------------------------------------------------------------------------
__global__ __launch_bounds__(256) void softmax_scale_kernel(
    const float* __restrict__ bp, const unsigned short* __restrict__ Wt,
    unsigned short* __restrict__ Wc) {
  int ju = blockIdx.x;          // 0..159
  int j = ju >> 4;
  int t = threadIdx.x;
  __shared__ float c[IC];
  __shared__ float red[256];
  for (int i = t; i < IC; i += 256) {
    float s = 0.0f;
#pragma unroll
    for (int p = 0; p < NP; ++p) s += bp[(size_t)p * (IC * NU) + j * IC + i];
    c[i] = s;
  }
  __syncthreads();
  float m = -1e30f;
  for (int i = t; i < IC; i += 256) m = fmaxf(m, c[i]);
  red[t] = m;
  __syncthreads();
  for (int o = 128; o > 0; o >>= 1) {
    if (t < o) red[t] = fmaxf(red[t], red[t + o]);
    __syncthreads();
  }
  float mx = red[0];
  __syncthreads();
  float sm = 0.0f;
  for (int i = t; i < IC; i += 256) {
    float e = __expf(c[i] - mx);
    c[i] = e;
    sm += e;
  }
  red[t] = sm;
  __syncthreads();
  for (int o = 128; o > 0; o >>= 1) {
    if (t < o) red[t] += red[t + o];
    __syncthreads();
  }
  float inv = 1.0f / red[0];
  // write one Wc row (9216 bf16 = 1152 x uint4), fully coalesced
  for (int q = t; q < KI / 8; q += 256) {
    int ki = q * 8;
    int i = ki % IC;            // chunk never straddles k (IC % 8 == 0)
    uint4 wv = *(const uint4*)&Wt[(size_t)ju * KI + ki];
    float4 cA = make_float4(c[i] * inv, c[i + 1] * inv, c[i + 2] * inv, c[i + 3] * inv);
    float4 cB = make_float4(c[i + 4] * inv, c[i + 5] * inv, c[i + 6] * inv, c[i + 7] * inv);
    *(uint4*)&Wc[(size_t)ju * KI + ki] = scale8(wv, cA, cB);
  }
}

// ---------------------------------------------------------------------------
extern "C" void kernel_launch(void* const* d_in, const int* in_sizes, int n_in,
                              void* d_out, int out_size, void* d_ws,
                              size_t ws_size, hipStream_t stream) {
  const float* x = (const float*)d_in[0];   // (512, 8, 1152)
  const float* W = (const float*)d_in[1];   // (1152, 10, 16, 8)
  float* out = (float*)d_out;               // (512, 10, 16)

  // workspace layout (~42 MB; harness provides ~268 MB)
  char* pws = (char*)d_ws;
  float* bp = (float*)pws;                     pws += (size_t)NP * IC * NU * 4;
  float* sp = (float*)pws;                     pws += (size_t)NSPLIT * B * JU * 4;
  float* Wr = (float*)pws;                     pws += (size_t)KI * JU * 4;
  unsigned short* xb = (unsigned short*)pws;   pws += (size_t)B * KI * 2;
  unsigned short* xT = (unsigned short*)pws;   pws += (size_t)KI * B * 2;
  unsigned short* Wt = (unsigned short*)pws;   pws += (size_t)JU * KI * 2;
  unsigned short* Wc = (unsigned short*)pws;   pws += (size_t)JU * KI * 2;
  unsigned short* vT = (unsigned short*)pws;

  prep_kernel<<<1152 + 144, 256, 0, stream>>>(x, W, xb, xT, Wt, Wc, Wr);

  for (int it = 0; it < 3; ++it) {
    s_gemm_mfma<<<dim3(8, NSPLIT, 2), 256, 0, stream>>>(xb, Wc, sp);
    squash_kernel<<<B, 192, 0, stream>>>(sp, vT, (it == 2) ? out : nullptr);
    if (it < 2) {
      b_update_mfma<<<dim3(144, NBS, 2), 256, 0, stream>>>(xT, vT, Wr, bp);
      softmax_scale_kernel<<<160, 256, 0, stream>>>(bp, Wt, Wc);
    }
  }
}